// Round 1
// baseline (20.179 us; speedup 1.0000x reference)
//
#include <hip/hip_runtime.h>
#include <math.h>

#define BATCH 512
#define HW 12544            // 112*112
#define PARTS 4             // blocks per sample in reduction kernel
#define VECS (HW / 4)       // 3136 float4 per plane
#define VEC_PER_PART (VECS / PARTS)  // 784

// Kernel 1: per-sample partial sums of squared diffs over the HW plane.
// blockIdx.x = b * PARTS + p.  Writes ws[(b*PARTS+p)*2 + {0,1}] = {er_part, sd_part}.
__global__ __launch_bounds__(256) void combine_loss_partials(
        const float* __restrict__ cams1,
        const float* __restrict__ cams2,
        const int* __restrict__ d_index,
        float* __restrict__ ws) {
    const int blk = blockIdx.x;
    const int b = blk / PARTS;
    const int p = blk % PARTS;
    const int tid = threadIdx.x;
    const int idx = d_index[0] & 1;

    // channel-1 plane of sample b: offset ((idx*B + b)*2 + 1) * HW
    const size_t cur_off = ((size_t)(idx * BATCH + b) * 2 + 1) * (size_t)HW;
    const size_t oth_off = ((size_t)((1 - idx) * BATCH + b) * 2 + 1) * (size_t)HW;

    const float4* __restrict__ c1 = (const float4*)(cams1 + cur_off);
    const float4* __restrict__ c2 = (const float4*)(cams2 + cur_off);
    const float4* __restrict__ tg = (const float4*)(cams1 + oth_off);

    float s_er = 0.f, s_sd = 0.f;
    const int start = p * VEC_PER_PART;
    const int end = start + VEC_PER_PART;
    for (int i = start + tid; i < end; i += 256) {
        float4 a = c1[i];
        float4 c = c2[i];
        float4 t = tg[i];
        float d0 = a.x - c.x, d1 = a.y - c.y, d2 = a.z - c.z, d3 = a.w - c.w;
        s_er += d0 * d0 + d1 * d1 + d2 * d2 + d3 * d3;
        float e0 = a.x - t.x, e1 = a.y - t.y, e2 = a.z - t.z, e3 = a.w - t.w;
        s_sd += e0 * e0 + e1 * e1 + e2 * e2 + e3 * e3;
    }

    // wave (64-lane) reduce
    for (int o = 32; o > 0; o >>= 1) {
        s_er += __shfl_down(s_er, o);
        s_sd += __shfl_down(s_sd, o);
    }
    __shared__ float r_er[4];
    __shared__ float r_sd[4];
    const int wid = tid >> 6;
    const int lane = tid & 63;
    if (lane == 0) { r_er[wid] = s_er; r_sd[wid] = s_sd; }
    __syncthreads();
    if (tid == 0) {
        float e = r_er[0] + r_er[1] + r_er[2] + r_er[3];
        float s = r_sd[0] + r_sd[1] + r_sd[2] + r_sd[3];
        ws[(size_t)(b * PARTS + p) * 2 + 0] = e;
        ws[(size_t)(b * PARTS + p) * 2 + 1] = s;
    }
}

// Kernel 2: per-sample scalar math + final reduction to one float.
// One block, 512 threads (thread b = sample b).
__global__ __launch_bounds__(512) void combine_loss_finalize(
        const float* __restrict__ preds1,
        const float* __restrict__ preds1_back,
        const float* __restrict__ preds2,
        const int* __restrict__ y,
        const int* __restrict__ d_index,
        const float* __restrict__ ws,
        float* __restrict__ out) {
    const int b = threadIdx.x;  // 0..511
    const int idx = d_index[0] & 1;

    // gather deterministic partials
    float er_sum = 0.f, sd_sum = 0.f;
    for (int p = 0; p < PARTS; ++p) {
        er_sum += ws[(size_t)(b * PARTS + p) * 2 + 0];
        sd_sum += ws[(size_t)(b * PARTS + p) * 2 + 1];
    }

    const float p1a = preds1[(size_t)(idx * BATCH + b) * 2 + 0];
    const float p1b = preds1[(size_t)(idx * BATCH + b) * 2 + 1];
    const float poa = preds1[(size_t)((1 - idx) * BATCH + b) * 2 + 0];
    const float pob = preds1[(size_t)((1 - idx) * BATCH + b) * 2 + 1];
    const float p2a = preds2[(size_t)(idx * BATCH + b) * 2 + 0];
    const float p2b = preds2[(size_t)(idx * BATCH + b) * 2 + 1];
    const float pba = preds1_back[(size_t)(idx * BATCH + b) * 2 + 0];
    const float pbb = preds1_back[(size_t)(idx * BATCH + b) * 2 + 1];
    const int yi = y[b];
    const float yf = (float)yi;

    // 2-class logsumexp
    auto lse2 = [](float a, float c) {
        float m = fmaxf(a, c);
        return m + logf(expf(a - m) + expf(c - m));
    };

    const float lse1 = lse2(p1a, p1b);
    const float lse_2 = lse2(p2a, p2b);
    const float lseb = lse2(pba, pbb);

    const float ce1 = lse1 - (yi == 1 ? p1b : p1a);
    const float ce2 = lse_2 - (yi == 1 ? p2b : p2a);
    const float ce = 0.5f * (ce1 + ce2);

    const float er = yf * (er_sum / (float)HW);
    const float ce_back = 0.5f * (lseb - pba) * yf;  // -log_softmax[:,0], masked

    const float prob1 = expf(p1b - lse1);            // softmax prob of class 1
    const int cur_pred = (p1b > p1a) ? 1 : 0;        // argmax (tie -> 0, matches jnp)
    const int flag_pred = (pob > poa) ? 1 : 0;

    const bool cond = (cur_pred != flag_pred) && (cur_pred == 0) && (yi == 1);
    const float w = cond ? prob1 : 1.0f;
    float loss_b = w * (ce + er + ce_back);

    const float same = (cur_pred == flag_pred) ? yf : 0.f;
    float sd_b = sd_sum * same;

    // block reduce (8 waves of 64)
    for (int o = 32; o > 0; o >>= 1) {
        loss_b += __shfl_down(loss_b, o);
        sd_b += __shfl_down(sd_b, o);
    }
    __shared__ float r_l[8];
    __shared__ float r_s[8];
    const int wid = b >> 6;
    const int lane = b & 63;
    if (lane == 0) { r_l[wid] = loss_b; r_s[wid] = sd_b; }
    __syncthreads();
    if (b == 0) {
        float ls = 0.f, ss = 0.f;
        for (int wv = 0; wv < 8; ++wv) { ls += r_l[wv]; ss += r_s[wv]; }
        out[0] = ls / (float)BATCH + ss / ((float)BATCH * (float)HW);
    }
}

extern "C" void kernel_launch(void* const* d_in, const int* in_sizes, int n_in,
                              void* d_out, int out_size, void* d_ws, size_t ws_size,
                              hipStream_t stream) {
    const float* preds1      = (const float*)d_in[0];
    const float* cams1       = (const float*)d_in[1];
    const float* preds1_back = (const float*)d_in[2];
    const float* preds2      = (const float*)d_in[3];
    const float* cams2       = (const float*)d_in[4];
    const int*   y           = (const int*)d_in[5];
    const int*   d_index     = (const int*)d_in[6];
    float* out = (float*)d_out;
    float* ws = (float*)d_ws;

    combine_loss_partials<<<BATCH * PARTS, 256, 0, stream>>>(cams1, cams2, d_index, ws);
    combine_loss_finalize<<<1, 512, 0, stream>>>(preds1, preds1_back, preds2, y,
                                                 d_index, ws, out);
}